// Round 10
// baseline (2227.598 us; speedup 1.0000x reference)
//
#include <hip/hip_runtime.h>
#include <math.h>

#define NN   16384      // total nodes
#define NE   262144     // edges (no self loops)
#define NB   64         // graphs
#define SEQT 256        // nodes per graph (= seq len)
#define DEP  64
#define DOUT 256        // = HID
#define G3   768        // 3*HID
#define GK   256        // GEMM K (always 256 here)

#define XPS  772        // xp LDS row stride (floats): 772%32=4 banks -> 2-way max
#define YSS  264        // y-stage LDS row stride (f16): 16B-aligned rows

typedef _Float16 h2_t   __attribute__((ext_vector_type(2)));
typedef _Float16 f16x8  __attribute__((ext_vector_type(8)));
typedef float    f32x4  __attribute__((ext_vector_type(4)));

static __device__ __forceinline__ h2_t pk(float a, float b) {
    return (h2_t)__builtin_amdgcn_cvt_pkrtz(a, b);
}

static __device__ __forceinline__ float fast_sigmoid(float v) {
    return __builtin_amdgcn_rcpf(1.f + __expf(-v));
}
static __device__ __forceinline__ float fast_tanh(float v) {
    return 1.f - 2.f * __builtin_amdgcn_rcpf(1.f + __expf(2.f * v));
}

// barrier with LDS-only drain (no vmcnt: in-flight global loads/stores cross)
static __device__ __forceinline__ void bar_lds() {
    asm volatile("s_waitcnt lgkmcnt(0)\n\ts_barrier" ::: "memory");
}

// ---------------------------------------------------------------------------
// degree / CSR build
// ---------------------------------------------------------------------------
__global__ void k_init_deg(int* deg) {
    int i = blockIdx.x * 256 + threadIdx.x;
    if (i < NN) deg[i] = 1;                       // self loop
}

__global__ void k_count(const int* __restrict__ ei, int* deg) {
    int e = blockIdx.x * 256 + threadIdx.x;
    if (e < NE) atomicAdd(&deg[ei[NE + e]], 1);   // col = dst
}

__global__ __launch_bounds__(1024) void k_scan_offs(const int* __restrict__ deg,
                                                    int* __restrict__ offs,
                                                    float* __restrict__ dinv) {
    __shared__ int lds[1024];
    const int tid = threadIdx.x;
    const int v0 = tid * 16;
    int loc[16];
    int s = 0;
#pragma unroll
    for (int i = 0; i < 16; ++i) {
        int d = deg[v0 + i];
        loc[i] = s;
        s += d - 1;                               // real in-edges only
        dinv[v0 + i] = rsqrtf((float)d);
    }
    lds[tid] = s;
    __syncthreads();
    for (int off = 1; off < 1024; off <<= 1) {
        int x = (tid >= off) ? lds[tid - off] : 0;
        __syncthreads();
        lds[tid] += x;
        __syncthreads();
    }
    int base = lds[tid] - s;                      // exclusive prefix of this thread
#pragma unroll
    for (int i = 0; i < 16; ++i) offs[v0 + i] = base + loc[i];
}

__global__ void k_fill(const int* __restrict__ ei, const int* __restrict__ offs,
                       int* cursor, int* __restrict__ eidx) {
    int e = blockIdx.x * 256 + threadIdx.x;
    if (e < NE) {
        int c = ei[NE + e];
        int pos = offs[c] + atomicAdd(&cursor[c], 1);
        eidx[pos] = e;
    }
}

__global__ void k_bself(const float* __restrict__ WB, float* Bself) {
    int f = threadIdx.x;                          // 256 threads
    float s = 0.f;
#pragma unroll
    for (int d = 0; d < DEP; ++d) s += WB[f * DEP + d];
    Bself[f] = s;
}

// fp32 -> f16 elementwise (n multiple of 1024); 4 elems/thread
__global__ void k_cvt(const float* __restrict__ in, _Float16* __restrict__ out) {
    int i = (blockIdx.x * 256 + threadIdx.x) * 4;
    float4 v = *(const float4*)(in + i);
    *(h2_t*)(out + i)     = pk(v.x, v.y);
    *(h2_t*)(out + i + 2) = pk(v.z, v.w);
}

// ---------------------------------------------------------------------------
// MFMA f16 GEMM: C[M,N] = A16[M,256] @ B16[N,256]^T (+ bias), fp32 out.
// Direct-from-L2, no LDS, no barriers.  Tile 128x128, wave owns 32 rows.
// (used only for the GCN's Ax projection now)
// ---------------------------------------------------------------------------
__global__ __launch_bounds__(256) void k_gemm16(const _Float16* __restrict__ A16,
                                                const _Float16* __restrict__ B16,
                                                const float* __restrict__ bias,
                                                float* __restrict__ C,
                                                int M, int N) {
    const int tid  = threadIdx.x;
    const int lane = tid & 63;
    const int wv   = tid >> 6;
    const int m0   = blockIdx.x * 128 + wv * 32;
    const int n0   = blockIdx.y * 128;
    const int ml   = lane & 15;
    const int quad = lane >> 4;

    const _Float16* ap0 = A16 + (size_t)(m0 + ml) * GK + quad * 8;
    const _Float16* ap1 = ap0 + (size_t)16 * GK;
    const _Float16* bp0 = B16 + (size_t)(n0 + ml) * GK + quad * 8;

    f32x4 acc[2][8];
#pragma unroll
    for (int i = 0; i < 2; ++i)
#pragma unroll
        for (int j = 0; j < 8; ++j) acc[i][j] = (f32x4){0.f, 0.f, 0.f, 0.f};

#pragma unroll 2
    for (int k0 = 0; k0 < GK; k0 += 32) {
        f16x8 a0 = *(const f16x8*)(ap0 + k0);
        f16x8 a1 = *(const f16x8*)(ap1 + k0);
#pragma unroll
        for (int nf = 0; nf < 8; ++nf) {
            f16x8 bf = *(const f16x8*)(bp0 + (size_t)nf * 16 * GK + k0);
            acc[0][nf] = __builtin_amdgcn_mfma_f32_16x16x32_f16(a0, bf, acc[0][nf], 0, 0, 0);
            acc[1][nf] = __builtin_amdgcn_mfma_f32_16x16x32_f16(a1, bf, acc[1][nf], 0, 0, 0);
        }
    }

#pragma unroll
    for (int mf = 0; mf < 2; ++mf)
#pragma unroll
        for (int nf = 0; nf < 8; ++nf) {
            const int col = n0 + nf * 16 + ml;
            const float bv = bias ? bias[col] : 0.f;
#pragma unroll
            for (int r = 0; r < 4; ++r) {
                const int row = m0 + mf * 16 + quad * 4 + r;
                C[(size_t)row * N + col] = acc[mf][nf][r] + bv;
            }
        }
}

// ---------------------------------------------------------------------------
// GCN gather: one WG (256 thr) per node.  WB row in registers (fused Be).
// ---------------------------------------------------------------------------
__global__ __launch_bounds__(256) void k_gcn(const float* __restrict__ Ax,
                                             const float* __restrict__ WB,
                                             const float* __restrict__ edge_attr,
                                             const int* __restrict__ ei,
                                             const int* __restrict__ eidx,
                                             const int* __restrict__ offs,
                                             const int* __restrict__ deg,
                                             const float* __restrict__ dinv,
                                             const float* __restrict__ Bself,
                                             const float* __restrict__ gcn_bias,
                                             _Float16* __restrict__ node16) {
    const int v = blockIdx.x;
    const int f = threadIdx.x;

    float wb[64];
#pragma unroll
    for (int d4 = 0; d4 < 16; ++d4) {
        float4 t = *(const float4*)&WB[f * DEP + d4 * 4];
        wb[d4 * 4 + 0] = t.x; wb[d4 * 4 + 1] = t.y;
        wb[d4 * 4 + 2] = t.z; wb[d4 * 4 + 3] = t.w;
    }

    __shared__ float ea[2][64];
    __shared__ int   src_s[2];
    const int base = offs[v];
    const int cnt  = deg[v] - 1;
    const float dv = dinv[v];
    float acc = 0.f;

    if (cnt > 0) {
        if (f < 64) {
            int e0 = eidx[base];
            ea[0][f] = edge_attr[(size_t)e0 * DEP + f];
            if (f == 0) src_s[0] = ei[e0];
        }
        __syncthreads();
        for (int i = 0; i < cnt; ++i) {
            int cur = i & 1;
            if (i + 1 < cnt && f < 64) {
                int e1 = eidx[base + i + 1];
                ea[cur ^ 1][f] = edge_attr[(size_t)e1 * DEP + f];
                if (f == 0) src_s[cur ^ 1] = ei[e1];
            }
            int s = src_s[cur];
            float be = 0.f;
#pragma unroll
            for (int d = 0; d < 64; ++d) be = fmaf(wb[d], ea[cur][d], be);
            float ax = Ax[(size_t)s * DOUT + f];
            acc = fmaf(dinv[s] * dv, tanhf(ax * be), acc);
            __syncthreads();
        }
    }
    // self loop: norm = dinv[v]^2, Be = rowsum(WB)
    acc += dv * dv * tanhf(Ax[(size_t)v * DOUT + f] * Bself[f]);
    float nv = tanhf(acc / (float)(cnt + 1) + gcn_bias[f]);
    node16[(size_t)v * DOUT + f] = (_Float16)nv;
}

// ---------------------------------------------------------------------------
// Fused 3-layer GRU + pooling + linear + softmax.  One 512-thr WG per graph.
// Per layer: 16 chunks of { stage 16 input rows -> LDS, MFMA chunk-GEMM
// xp(16x768) -> LDS, 16 scan steps (R9 structure, xp from LDS) }.
// w_hh held as A-fragments (48/wave -> AGPR half of unified file).
// Eliminates: 3 xp GEMM dispatches + global xp stream (150 MB HBM/iter),
// k_final dispatch, all inter-layer launch gaps.
// ---------------------------------------------------------------------------
__global__ __launch_bounds__(512, 2) void k_gru_all(
        const _Float16* __restrict__ in0,     // node16 [NN][256]
        const _Float16* __restrict__ wih16,   // [3][768][256]
        const _Float16* __restrict__ whh16,   // [3][768][256]
        const float* __restrict__ bih0, const float* __restrict__ bih1,
        const float* __restrict__ bih2,
        const float* __restrict__ bhh0, const float* __restrict__ bhh1,
        const float* __restrict__ bhh2,
        _Float16* __restrict__ bufA,          // y of layer 0 and 2
        _Float16* __restrict__ bufB,          // y of layer 1
        const float* __restrict__ lin_W,
        const float* __restrict__ lin_b,
        float* __restrict__ out) {
    const int tid  = threadIdx.x;
    const int b    = blockIdx.x;              // graph
    const int lane = tid & 63;
    const int wv   = tid >> 6;                // wave 0..7
    const int ml   = lane & 15;
    const int quad = lane >> 4;
    const bool gate = tid < 256;

    __shared__ float    xp_s[16 * XPS];       // 49408 B  (xp chunk, fp32)
    __shared__ _Float16 yst[16 * YSS];        //  8448 B  (staged input rows)
    __shared__ _Float16 h16[2][256];          //  1024 B  (h, dbuf by parity)
    __shared__ float    ghL[768];             //  3072 B  (w_hh @ h)
    __shared__ float    hTs[3 * 256];         //  3072 B  (per-layer final h)
                                              // total 65024 <= 65536

    const float* bihL[3] = {bih0, bih1, bih2};
    const float* bhhL[3] = {bhh0, bhh1, bhh2};

    for (int l = 0; l < 3; ++l) {
        // --- recurrent weights -> A-fragments (f16, pre-converted) ---
        f16x8 A[6][8];
        {
            const _Float16* whhl = whh16 + (size_t)l * G3 * 256;
#pragma unroll
            for (int rb = 0; rb < 6; ++rb) {
                const int row = wv * 96 + rb * 16 + ml;
#pragma unroll
                for (int kt = 0; kt < 8; ++kt)
                    A[rb][kt] = *(const f16x8*)(whhl + (size_t)row * 256
                                                + kt * 32 + quad * 8);
            }
        }
        float bhr = 0.f, bhz = 0.f, bhn = 0.f;
        float bir = 0.f, biz = 0.f, bin_ = 0.f;
        if (gate) {
            const float* bh = bhhL[l];
            const float* bi = bihL[l];
            bhr = bh[tid]; bhz = bh[256 + tid]; bhn = bh[512 + tid];
            bir = bi[tid]; biz = bi[256 + tid]; bin_ = bi[512 + tid];
        }
        float h_old = 0.f;
        if (gate) h16[0][tid] = (_Float16)0.f;

        const _Float16* inbuf  = (l == 0 ? in0 : (l == 1 ? bufA : bufB))
                               + (size_t)b * SEQT * DOUT;
        _Float16*       outbuf = (l == 0 ? bufA : (l == 1 ? bufB : bufA))
                               + (size_t)b * SEQT * DOUT;
        const _Float16* wihl   = wih16 + (size_t)l * G3 * 256;

        for (int c = 0; c < 16; ++c) {
            // --- stage the chunk's 16 input rows (global -> LDS) ---
            {
                const int r = tid >> 5, g = tid & 31;
                *(f16x8*)&yst[r * YSS + g * 8] =
                    *(const f16x8*)(inbuf + (size_t)(c * 16 + r) * DOUT + g * 8);
            }
            __syncthreads();                  // staging complete (vmcnt+lgkm)

            // --- chunk GEMM: xp[j][t] for t in chunk, j = gate rows ---
            // wave wv owns gate-row blocks rbg = 6wv..6wv+5
#pragma unroll
            for (int rb = 0; rb < 6; ++rb) {
                const int rbg = wv * 6 + rb;
                f16x8 Aa[8];
#pragma unroll
                for (int kt = 0; kt < 8; ++kt)
                    Aa[kt] = *(const f16x8*)(wihl + (size_t)(rbg * 16 + ml) * 256
                                             + kt * 32 + quad * 8);
                f32x4 Cc = {0.f, 0.f, 0.f, 0.f};
#pragma unroll
                for (int kt = 0; kt < 8; ++kt) {
                    f16x8 bf = *(const f16x8*)&yst[ml * YSS + kt * 32 + quad * 8];
                    Cc = __builtin_amdgcn_mfma_f32_16x16x32_f16(Aa[kt], bf, Cc, 0, 0, 0);
                }
                // C: col = t = ml, rows = rbg*16 + quad*4 + r  (contiguous j)
                *(f32x4*)&xp_s[ml * XPS + rbg * 16 + quad * 4] = Cc;
            }
            bar_lds();                        // xp chunk visible

            // --- 16 scan steps (R9 structure, xp from LDS) ---
            for (int ts = 0; ts < 16; ++ts) {
                const int t = c * 16 + ts;
                const _Float16* hcur = h16[t & 1];
                f32x4 C6[6];
#pragma unroll
                for (int rb = 0; rb < 6; ++rb) C6[rb] = (f32x4){0.f, 0.f, 0.f, 0.f};

                union { f16x8 v; float4 f; } Bk, Bn;
                Bk.f = *(const float4*)&hcur[quad * 8];
#pragma unroll
                for (int kt = 0; kt < 8; ++kt) {
                    if (kt < 7) Bn.f = *(const float4*)&hcur[(kt + 1) * 32 + quad * 8];
#pragma unroll
                    for (int rb = 0; rb < 6; ++rb)
                        C6[rb] = __builtin_amdgcn_mfma_f32_16x16x32_f16(A[rb][kt], Bk.v, C6[rb], 0, 0, 0);
                    Bk.v = Bn.v;
                }
                if (ml == 0) {                // col-0 lanes hold the matvec
#pragma unroll
                    for (int rb = 0; rb < 6; ++rb)
                        *(f32x4*)&ghL[wv * 96 + rb * 16 + quad * 4] = C6[rb];
                }
                bar_lds();                    // gh visible

                if (gate) {
                    const int j = tid;
                    float ghr = ghL[j]       + bhr;
                    float ghz = ghL[256 + j] + bhz;
                    float ghn = ghL[512 + j] + bhn;
                    float xr = xp_s[ts * XPS + j]       + bir;
                    float xz = xp_s[ts * XPS + 256 + j] + biz;
                    float xn = xp_s[ts * XPS + 512 + j] + bin_;
                    float r = fast_sigmoid(xr + ghr);
                    float z = fast_sigmoid(xz + ghz);
                    float n = fast_tanh(xn + r * ghn);
                    float hn = (1.f - z) * n + z * h_old;
                    h_old = hn;
                    h16[(t & 1) ^ 1][j] = (_Float16)hn;
                    outbuf[(size_t)t * DOUT + j] = (_Float16)hn;
                    if (t == SEQT - 1) hTs[l * 256 + j] = hn;
                }
                bar_lds();                    // publish h(t+1)
            }
        }
        // y of this layer must be L2-visible for next layer's staging reads
        __threadfence();
        __syncthreads();
    }

    // --- pooling + linear + softmax (xp_s reused as scratch) ---
    const _Float16* y2 = bufA + (size_t)b * SEQT * DOUT;   // layer-2 output
    float* pool = xp_s;                       // [1280]
    float* red  = xp_s + 1536;                // [2][256]
    if (gate) {
        const int j = tid;
        float mx = -1e30f, sm = 0.f;
        for (int t = 0; t < SEQT; ++t) {
            float v = (float)y2[(size_t)t * DOUT + j];
            mx = fmaxf(mx, v);
            sm += v;
        }
        pool[j]        = hTs[j];
        pool[256 + j]  = hTs[256 + j];
        pool[512 + j]  = hTs[512 + j];
        pool[768 + j]  = mx;
        pool[1024 + j] = sm * (1.f / 256.f);
    }
    __syncthreads();
    if (gate) {
        float p0 = 0.f, p1 = 0.f;
        for (int i = tid; i < 1280; i += 256) {
            float pv = pool[i];
            p0 = fmaf(lin_W[i], pv, p0);
            p1 = fmaf(lin_W[1280 + i], pv, p1);
        }
        red[tid] = p0; red[256 + tid] = p1;
    }
    __syncthreads();
    if (tid == 0) {
        float l0 = lin_b[0], l1 = lin_b[1];
        for (int i = 0; i < 256; ++i) { l0 += red[i]; l1 += red[256 + i]; }
        float m = fmaxf(l0, l1);
        float e0 = __expf(l0 - m), e1 = __expf(l1 - m);
        float s = e0 + e1;
        out[b * 2 + 0] = e0 / s;
        out[b * 2 + 1] = e1 / s;
    }
}

// ---------------------------------------------------------------------------
extern "C" void kernel_launch(void* const* d_in, const int* in_sizes, int n_in,
                              void* d_out, int out_size, void* d_ws, size_t ws_size,
                              hipStream_t stream) {
    const float* x         = (const float*)d_in[0];
    const float* edge_attr = (const float*)d_in[1];
    const int*   ei        = (const int*)d_in[2];
    const float* WA        = (const float*)d_in[3];
    const float* WB        = (const float*)d_in[4];
    const float* gcn_bias  = (const float*)d_in[5];
    const float* w_ih[3] = {(const float*)d_in[6],  (const float*)d_in[10], (const float*)d_in[14]};
    const float* w_hh[3] = {(const float*)d_in[7],  (const float*)d_in[11], (const float*)d_in[15]};
    const float* b_ih[3] = {(const float*)d_in[8],  (const float*)d_in[12], (const float*)d_in[16]};
    const float* b_hh[3] = {(const float*)d_in[9],  (const float*)d_in[13], (const float*)d_in[17]};
    const float* lin_W = (const float*)d_in[18];
    const float* lin_b = (const float*)d_in[19];
    float* out = (float*)d_out;

    char* p = (char*)d_ws;
    auto alloc = [&](size_t bytes) {
        char* r = p;
        p += (bytes + 255) & ~(size_t)255;
        return r;
    };
    int*   deg    = (int*)alloc((size_t)NN * 4);
    int*   offs   = (int*)alloc((size_t)NN * 4);
    int*   cursor = (int*)alloc((size_t)NN * 4);
    float* dinv   = (float*)alloc((size_t)NN * 4);
    int*   eidx   = (int*)alloc((size_t)NE * 4);
    float* Bself  = (float*)alloc(256 * 4);
    float* Ax     = (float*)alloc((size_t)NN * DOUT * 4);

    _Float16* node16 = (_Float16*)alloc((size_t)NN * DOUT * 2);
    _Float16* bufA   = (_Float16*)alloc((size_t)NN * DOUT * 2);
    _Float16* x16    = (_Float16*)alloc((size_t)NN * DOUT * 2);
    _Float16* bufB   = x16;  // alias: x16 dead after Ax GEMM, bufB live later
    _Float16* WA16   = (_Float16*)alloc((size_t)256 * 256 * 2);
    _Float16* wih16  = (_Float16*)alloc((size_t)3 * G3 * 256 * 2);
    _Float16* whh16  = (_Float16*)alloc((size_t)3 * G3 * 256 * 2);

    // --- CSR build + weight conversions ---
    hipMemsetAsync(cursor, 0, (size_t)NN * 4, stream);
    k_init_deg<<<NN / 256, 256, 0, stream>>>(deg);
    k_count<<<NE / 256, 256, 0, stream>>>(ei, deg);
    k_scan_offs<<<1, 1024, 0, stream>>>(deg, offs, dinv);
    k_fill<<<NE / 256, 256, 0, stream>>>(ei, offs, cursor, eidx);
    k_bself<<<1, 256, 0, stream>>>(WB, Bself);
    k_cvt<<<(NN * DOUT) / 1024, 256, 0, stream>>>(x, x16);
    k_cvt<<<(256 * 256) / 1024, 256, 0, stream>>>(WA, WA16);
    for (int l = 0; l < 3; ++l) {
        k_cvt<<<(G3 * 256) / 1024, 256, 0, stream>>>(w_ih[l], wih16 + (size_t)l * G3 * 256);
        k_cvt<<<(G3 * 256) / 1024, 256, 0, stream>>>(w_hh[l], whh16 + (size_t)l * G3 * 256);
    }

    // --- GCN ---
    {
        dim3 g(NN / 128, 256 / 128);
        k_gemm16<<<g, 256, 0, stream>>>(x16, WA16, nullptr, Ax, NN, 256);
    }
    k_gcn<<<NN, 256, 0, stream>>>(Ax, WB, edge_attr, ei, eidx, offs, deg, dinv,
                                  Bself, gcn_bias, node16);

    // --- fused GRU x3 + pooling + linear + softmax ---
    k_gru_all<<<NB, 512, 0, stream>>>(node16, wih16, whh16,
                                      b_ih[0], b_ih[1], b_ih[2],
                                      b_hh[0], b_hh[1], b_hh[2],
                                      bufA, bufB, lin_W, lin_b, out);
}

// Round 11
// 1678.716 us; speedup vs baseline: 1.3270x; 1.3270x over previous
//
#include <hip/hip_runtime.h>
#include <math.h>

#define NN   16384      // total nodes
#define NE   262144     // edges (no self loops)
#define NB   64         // graphs
#define SEQT 256        // nodes per graph (= seq len)
#define DEP  64
#define DOUT 256        // = HID
#define G3   768        // 3*HID
#define GK   256        // GEMM K (always 256 here)
#define ECAP 32         // GCN edges staged per chunk

typedef _Float16 h2_t   __attribute__((ext_vector_type(2)));
typedef _Float16 f16x8  __attribute__((ext_vector_type(8)));
typedef float    f32x4  __attribute__((ext_vector_type(4)));

static __device__ __forceinline__ h2_t pk(float a, float b) {
    return (h2_t)__builtin_amdgcn_cvt_pkrtz(a, b);
}

static __device__ __forceinline__ float fast_sigmoid(float v) {
    return __builtin_amdgcn_rcpf(1.f + __expf(-v));
}
static __device__ __forceinline__ float fast_tanh(float v) {
    return 1.f - 2.f * __builtin_amdgcn_rcpf(1.f + __expf(2.f * v));
}

// barrier with LDS-only drain (no vmcnt: in-flight global loads/stores cross)
static __device__ __forceinline__ void bar_lds() {
    asm volatile("s_waitcnt lgkmcnt(0)\n\ts_barrier" ::: "memory");
}

// ---------------------------------------------------------------------------
// degree / CSR build (deg zero-initialized by memset; holds RAW in-degree)
// ---------------------------------------------------------------------------
__global__ void k_count(const int* __restrict__ ei, int* deg) {
    int e = blockIdx.x * 256 + threadIdx.x;
    if (e < NE) atomicAdd(&deg[ei[NE + e]], 1);   // col = dst
}

__global__ __launch_bounds__(1024) void k_scan_offs(const int* __restrict__ deg,
                                                    int* __restrict__ offs,
                                                    float* __restrict__ dinv) {
    __shared__ int lds[1024];
    const int tid = threadIdx.x;
    const int v0 = tid * 16;
    int loc[16];
    int s = 0;
#pragma unroll
    for (int i = 0; i < 16; ++i) {
        int d = deg[v0 + i];                      // raw in-edges
        loc[i] = s;
        s += d;
        dinv[v0 + i] = rsqrtf((float)(d + 1));    // +1 self loop
    }
    lds[tid] = s;
    __syncthreads();
    for (int off = 1; off < 1024; off <<= 1) {
        int x = (tid >= off) ? lds[tid - off] : 0;
        __syncthreads();
        lds[tid] += x;
        __syncthreads();
    }
    int base = lds[tid] - s;                      // exclusive prefix of this thread
#pragma unroll
    for (int i = 0; i < 16; ++i) offs[v0 + i] = base + loc[i];
}

__global__ void k_fill(const int* __restrict__ ei, const int* __restrict__ offs,
                       int* cursor, int* __restrict__ eidx) {
    int e = blockIdx.x * 256 + threadIdx.x;
    if (e < NE) {
        int c = ei[NE + e];
        int pos = offs[c] + atomicAdd(&cursor[c], 1);
        eidx[pos] = e;
    }
}

__global__ void k_bself(const float* __restrict__ WB, float* Bself) {
    int f = threadIdx.x;                          // 256 threads
    float s = 0.f;
#pragma unroll
    for (int d = 0; d < DEP; ++d) s += WB[f * DEP + d];
    Bself[f] = s;
}

// ---------------------------------------------------------------------------
// one fused fp32->f16 conversion over all 5 regions (was 5 dispatches)
// region sizes: x 4194304 | WA 65536 | w_ih[l] 196608 x3  (all /1024 exact)
// ---------------------------------------------------------------------------
__global__ void k_cvt_all(const float* __restrict__ x,  const float* __restrict__ wa,
                          const float* __restrict__ w0, const float* __restrict__ w1,
                          const float* __restrict__ w2,
                          _Float16* __restrict__ xo,  _Float16* __restrict__ wao,
                          _Float16* __restrict__ w0o, _Float16* __restrict__ w1o,
                          _Float16* __restrict__ w2o) {
    size_t i = ((size_t)blockIdx.x * 256 + threadIdx.x) * 4;
    const size_t B0 = 4194304, B1 = B0 + 65536, B2 = B1 + 196608, B3 = B2 + 196608;
    const float* in; _Float16* out; size_t off;
    if      (i < B0) { in = x;  out = xo;  off = i; }
    else if (i < B1) { in = wa; out = wao; off = i - B0; }
    else if (i < B2) { in = w0; out = w0o; off = i - B1; }
    else if (i < B3) { in = w1; out = w1o; off = i - B2; }
    else             { in = w2; out = w2o; off = i - B3; }
    float4 v = *(const float4*)(in + off);
    *(h2_t*)(out + off)     = pk(v.x, v.y);
    *(h2_t*)(out + off + 2) = pk(v.z, v.w);
}

// ---------------------------------------------------------------------------
// MFMA f16 GEMM: C[M,N] = A16[M,256] @ B16[N,256]^T (+ bias), fp32 out.
// Direct-from-L2, no LDS, no barriers.  Tile 128x128, wave owns 32 rows.
// ---------------------------------------------------------------------------
__global__ __launch_bounds__(256) void k_gemm16(const _Float16* __restrict__ A16,
                                                const _Float16* __restrict__ B16,
                                                const float* __restrict__ bias,
                                                float* __restrict__ C,
                                                int M, int N) {
    const int tid  = threadIdx.x;
    const int lane = tid & 63;
    const int wv   = tid >> 6;
    const int m0   = blockIdx.x * 128 + wv * 32;
    const int n0   = blockIdx.y * 128;
    const int ml   = lane & 15;
    const int quad = lane >> 4;

    const _Float16* ap0 = A16 + (size_t)(m0 + ml) * GK + quad * 8;
    const _Float16* ap1 = ap0 + (size_t)16 * GK;
    const _Float16* bp0 = B16 + (size_t)(n0 + ml) * GK + quad * 8;

    f32x4 acc[2][8];
#pragma unroll
    for (int i = 0; i < 2; ++i)
#pragma unroll
        for (int j = 0; j < 8; ++j) acc[i][j] = (f32x4){0.f, 0.f, 0.f, 0.f};

#pragma unroll 2
    for (int k0 = 0; k0 < GK; k0 += 32) {
        f16x8 a0 = *(const f16x8*)(ap0 + k0);
        f16x8 a1 = *(const f16x8*)(ap1 + k0);
#pragma unroll
        for (int nf = 0; nf < 8; ++nf) {
            f16x8 bf = *(const f16x8*)(bp0 + (size_t)nf * 16 * GK + k0);
            acc[0][nf] = __builtin_amdgcn_mfma_f32_16x16x32_f16(a0, bf, acc[0][nf], 0, 0, 0);
            acc[1][nf] = __builtin_amdgcn_mfma_f32_16x16x32_f16(a1, bf, acc[1][nf], 0, 0, 0);
        }
    }

#pragma unroll
    for (int mf = 0; mf < 2; ++mf)
#pragma unroll
        for (int nf = 0; nf < 8; ++nf) {
            const int col = n0 + nf * 16 + ml;
            const float bv = bias ? bias[col] : 0.f;
#pragma unroll
            for (int r = 0; r < 4; ++r) {
                const int row = m0 + mf * 16 + quad * 4 + r;
                C[(size_t)row * N + col] = acc[mf][nf][r] + bv;
            }
        }
}

// ---------------------------------------------------------------------------
// GCN gather v2: one WG (256 thr) per node.  Chunked LDS staging: 2 syncs
// per 32-edge chunk instead of 2 per edge (old version was sync-bound:
// ~3400 sync cyc vs ~2176 FMA cyc per node).  fast_tanh (libm tanhf ~3x).
// ---------------------------------------------------------------------------
__global__ __launch_bounds__(256) void k_gcn(const float* __restrict__ Ax,
                                             const float* __restrict__ WB,
                                             const float* __restrict__ edge_attr,
                                             const int* __restrict__ ei,
                                             const int* __restrict__ eidx,
                                             const int* __restrict__ offs,
                                             const int* __restrict__ deg,
                                             const float* __restrict__ dinv,
                                             const float* __restrict__ Bself,
                                             const float* __restrict__ gcn_bias,
                                             _Float16* __restrict__ node16) {
    const int v = blockIdx.x;
    const int f = threadIdx.x;

    float wb[64];
#pragma unroll
    for (int d4 = 0; d4 < 16; ++d4) {
        float4 t = *(const float4*)&WB[f * DEP + d4 * 4];
        wb[d4 * 4 + 0] = t.x; wb[d4 * 4 + 1] = t.y;
        wb[d4 * 4 + 2] = t.z; wb[d4 * 4 + 3] = t.w;
    }

    __shared__ float ea_s[ECAP * 64];
    __shared__ int   es_s[ECAP];
    __shared__ int   src_s[ECAP];
    __shared__ float nrm_s[ECAP];

    const int   base = offs[v];
    const int   cnt  = deg[v];                   // raw in-edges
    const float dv   = dinv[v];
    float acc = 0.f;

    for (int c0 = 0; c0 < cnt; c0 += ECAP) {
        const int n = min(ECAP, cnt - c0);
        if (f < n) {
            int e = eidx[base + c0 + f];
            es_s[f] = e;
            int s = ei[e];
            src_s[f] = s;
            nrm_s[f] = dinv[s] * dv;
        }
        __syncthreads();
        for (int idx = f; idx < n * 64; idx += 256) {
            int el = idx >> 6, d = idx & 63;
            ea_s[idx] = edge_attr[(size_t)es_s[el] * DEP + d];
        }
        __syncthreads();
        for (int i = 0; i < n; ++i) {
            float ax = Ax[(size_t)src_s[i] * DOUT + f];   // issued early
            float be = 0.f;
#pragma unroll
            for (int d = 0; d < 64; ++d) be = fmaf(wb[d], ea_s[i * 64 + d], be);
            acc = fmaf(nrm_s[i], fast_tanh(ax * be), acc);
        }
        __syncthreads();                          // before chunk overwrite
    }
    // self loop: norm = dinv^2, Be = rowsum(WB)
    acc += dv * dv * fast_tanh(Ax[(size_t)v * DOUT + f] * Bself[f]);
    float nv = fast_tanh(acc / (float)(cnt + 1) + gcn_bias[f]);
    node16[(size_t)v * DOUT + f] = (_Float16)nv;
}

// ---------------------------------------------------------------------------
// GRU scan (R9 structure, unchanged core): 512-thr WG (8 waves = 2/SIMD) per
// graph; w_hh A-frags 48/wave (AGPR-class); k-outer MFMA, 6 indep chains.
// NEW: layer==2 fuses pooling+linear+softmax (max/sum accumulated in gate
// registers across t for free) and skips the dead y16 store.
// ---------------------------------------------------------------------------
__global__ __launch_bounds__(512, 2) void k_gru_scan(const float* __restrict__ xp,
                                                     const float* __restrict__ w_hh,
                                                     const float* __restrict__ b_hh,
                                                     _Float16* __restrict__ y16,
                                                     float* __restrict__ hT_all,
                                                     int layer,
                                                     const float* __restrict__ lin_W,
                                                     const float* __restrict__ lin_b,
                                                     float* __restrict__ out) {
    const int tid  = threadIdx.x;
    const int b    = blockIdx.x;                 // graph
    const int lane = tid & 63;
    const int wv   = tid >> 6;                   // wave 0..7
    const int m    = lane & 15;                  // A-frag row within 16
    const int quad = lane >> 4;                  // 0..3 (k-subgroup)
    const bool gate = tid < 256;

    // --- weights -> A-fragments (one-time global read, fp32 -> f16) ---
    f16x8 A[6][8];
#pragma unroll
    for (int rb = 0; rb < 6; ++rb) {
        const int row = wv * 96 + rb * 16 + m;
#pragma unroll
        for (int kt = 0; kt < 8; ++kt) {
            const float* wp = w_hh + (size_t)row * 256 + kt * 32 + quad * 8;
            float4 a0 = *(const float4*)wp;
            float4 a1 = *(const float4*)(wp + 4);
            union { f16x8 v; h2_t h[4]; } u;
            u.h[0] = pk(a0.x, a0.y); u.h[1] = pk(a0.z, a0.w);
            u.h[2] = pk(a1.x, a1.y); u.h[3] = pk(a1.z, a1.w);
            A[rb][kt] = u.v;
        }
    }

    float bhr = 0.f, bhz = 0.f, bhn = 0.f;
    if (gate) {
        bhr = b_hh[tid]; bhz = b_hh[256 + tid]; bhn = b_hh[512 + tid];
    }

    __shared__ _Float16 h16[2][256];             // h(t) f16, double-buffered
    __shared__ float    ghL[768];                // w_hh @ h
    __shared__ float    pool[1280];              // layer-2 epilogue only
    __shared__ float    red[512];
    float h_old = 0.f;                           // thread tid<256 owns h[tid]
    if (gate) h16[0][tid] = (_Float16)0.f;
    __syncthreads();

    const float* xpb  = xp  + (size_t)b * SEQT * G3;
    _Float16*    yb16 = y16 + (size_t)b * SEQT * DOUT;

    float mx = -1e30f, sm = 0.f;                 // layer-2 pooling accum

    for (int t = 0; t < SEQT; ++t) {
        // prefetch this step's xp (vmcnt-waited at gate use, overlaps MFMA)
        float xr = 0.f, xz = 0.f, xn = 0.f;
        if (gate) {
            const float* xpt = xpb + (size_t)t * G3 + tid;
            xr = xpt[0]; xz = xpt[256]; xn = xpt[512];
        }

        // k-outer MFMA: one B-frag per kt feeds 6 independent chains
        const _Float16* hcur = h16[t & 1];
        f32x4 C[6];
#pragma unroll
        for (int rb = 0; rb < 6; ++rb) C[rb] = (f32x4){0.f, 0.f, 0.f, 0.f};

        union { f16x8 v; float4 f; } Bk, Bn;
        Bk.f = *(const float4*)&hcur[quad * 8];
#pragma unroll
        for (int kt = 0; kt < 8; ++kt) {
            if (kt < 7) Bn.f = *(const float4*)&hcur[(kt + 1) * 32 + quad * 8];
#pragma unroll
            for (int rb = 0; rb < 6; ++rb)
                C[rb] = __builtin_amdgcn_mfma_f32_16x16x32_f16(A[rb][kt], Bk.v, C[rb], 0, 0, 0);
            Bk.v = Bn.v;
        }
        if (m == 0) {                            // col-0 lanes hold the matvec
#pragma unroll
            for (int rb = 0; rb < 6; ++rb)
                *(f32x4*)&ghL[wv * 96 + rb * 16 + quad * 4] = C[rb];
        }
        bar_lds();                               // gh visible to gate waves

        if (gate) {
            const int j = tid;
            float ghr = ghL[j]       + bhr;
            float ghz = ghL[256 + j] + bhz;
            float ghn = ghL[512 + j] + bhn;
            float r = fast_sigmoid(xr + ghr);
            float z = fast_sigmoid(xz + ghz);
            float n = fast_tanh(xn + r * ghn);
            float hn = (1.f - z) * n + z * h_old;
            h_old = hn;
            h16[(t & 1) ^ 1][j] = (_Float16)hn;  // next step's buffer
            if (layer < 2) {
                yb16[(size_t)t * DOUT + j] = (_Float16)hn;
                if (t == SEQT - 1) hT_all[layer * NB * 256 + b * 256 + j] = hn;
            } else {
                mx = fmaxf(mx, hn);
                sm += hn;
            }
        }
        bar_lds();                               // publish h(t+1)
    }

    if (layer == 2) {
        // --- fused pooling + linear + softmax ---
        if (gate) {
            const int j = tid;
            pool[j]        = hT_all[b * 256 + j];               // layer-0 hT
            pool[256 + j]  = hT_all[NB * 256 + b * 256 + j];    // layer-1 hT
            pool[512 + j]  = h_old;                             // layer-2 hT
            pool[768 + j]  = mx;
            pool[1024 + j] = sm * (1.f / 256.f);
        }
        __syncthreads();
        if (gate) {
            float p0 = 0.f, p1 = 0.f;
            for (int i = tid; i < 1280; i += 256) {
                float pv = pool[i];
                p0 = fmaf(lin_W[i], pv, p0);
                p1 = fmaf(lin_W[1280 + i], pv, p1);
            }
            red[tid] = p0; red[256 + tid] = p1;
        }
        __syncthreads();
        if (tid == 0) {
            float l0 = lin_b[0], l1 = lin_b[1];
            for (int i = 0; i < 256; ++i) { l0 += red[i]; l1 += red[256 + i]; }
            float m2 = fmaxf(l0, l1);
            float e0 = __expf(l0 - m2), e1 = __expf(l1 - m2);
            float s = e0 + e1;
            out[b * 2 + 0] = e0 / s;
            out[b * 2 + 1] = e1 / s;
        }
    }
}

// ---------------------------------------------------------------------------
extern "C" void kernel_launch(void* const* d_in, const int* in_sizes, int n_in,
                              void* d_out, int out_size, void* d_ws, size_t ws_size,
                              hipStream_t stream) {
    const float* x         = (const float*)d_in[0];
    const float* edge_attr = (const float*)d_in[1];
    const int*   ei        = (const int*)d_in[2];
    const float* WA        = (const float*)d_in[3];
    const float* WB        = (const float*)d_in[4];
    const float* gcn_bias  = (const float*)d_in[5];
    const float* w_ih[3] = {(const float*)d_in[6],  (const float*)d_in[10], (const float*)d_in[14]};
    const float* w_hh[3] = {(const float*)d_in[7],  (const float*)d_in[11], (const float*)d_in[15]};
    const float* b_ih[3] = {(const float*)d_in[8],  (const float*)d_in[12], (const float*)d_in[16]};
    const float* b_hh[3] = {(const float*)d_in[9],  (const float*)d_in[13], (const float*)d_in[17]};
    const float* lin_W = (const float*)d_in[18];
    const float* lin_b = (const float*)d_in[19];
    float* out = (float*)d_out;

    char* p = (char*)d_ws;
    auto alloc = [&](size_t bytes) {
        char* r = p;
        p += (bytes + 255) & ~(size_t)255;
        return r;
    };
    int*   deg    = (int*)alloc((size_t)NN * 4);   // ┐ contiguous: one memset
    int*   offs   = (int*)alloc((size_t)NN * 4);   // │
    int*   cursor = (int*)alloc((size_t)NN * 4);   // ┘
    float* dinv   = (float*)alloc((size_t)NN * 4);
    int*   eidx   = (int*)alloc((size_t)NE * 4);
    float* Bself  = (float*)alloc(256 * 4);
    float* hT     = (float*)alloc(2 * NB * 256 * 4);
    float* xp     = (float*)alloc((size_t)NN * G3 * 4);
    float* Ax     = xp;   // alias: Ax dead before xp is first written

    _Float16* node16 = (_Float16*)alloc((size_t)NN * DOUT * 2);
    _Float16* yA16   = (_Float16*)alloc((size_t)NN * DOUT * 2);
    _Float16* x16    = (_Float16*)alloc((size_t)NN * DOUT * 2);
    _Float16* yB16   = x16;  // alias: x16 dead after Ax GEMM, yB16 live later
    _Float16* WA16   = (_Float16*)alloc((size_t)256 * 256 * 2);
    _Float16* wih16[3];
    for (int l = 0; l < 3; ++l) wih16[l] = (_Float16*)alloc((size_t)G3 * 256 * 2);

    // --- CSR build + weight conversions ---
    hipMemsetAsync(deg, 0, (size_t)3 * NN * 4, stream);    // deg+offs+cursor
    k_count<<<NE / 256, 256, 0, stream>>>(ei, deg);
    k_scan_offs<<<1, 1024, 0, stream>>>(deg, offs, dinv);
    k_fill<<<NE / 256, 256, 0, stream>>>(ei, offs, cursor, eidx);
    k_bself<<<1, 256, 0, stream>>>(WB, Bself);
    k_cvt_all<<<4736, 256, 0, stream>>>(x, WA, w_ih[0], w_ih[1], w_ih[2],
                                        x16, WA16, wih16[0], wih16[1], wih16[2]);

    // --- GCN ---
    {
        dim3 g(NN / 128, 256 / 128);
        k_gemm16<<<g, 256, 0, stream>>>(x16, WA16, nullptr, Ax, NN, 256);
    }
    k_gcn<<<NN, 256, 0, stream>>>(Ax, WB, edge_attr, ei, eidx, offs, deg, dinv,
                                  Bself, gcn_bias, node16);

    // --- GRU x3 (layer 2 fuses pooling+linear+softmax) ---
    const _Float16* in16 = node16;
    _Float16* y16_outs[3] = {yA16, yB16, yA16};
    for (int l = 0; l < 3; ++l) {
        dim3 g(NN / 128, G3 / 128);
        k_gemm16<<<g, 256, 0, stream>>>(in16, wih16[l], b_ih[l], xp, NN, G3);
        k_gru_scan<<<NB, 512, 0, stream>>>(xp, w_hh[l], b_hh[l], y16_outs[l],
                                           hT, l, lin_W, lin_b, out);
        in16 = y16_outs[l];
    }
}